// Round 2
// baseline (224.441 us; speedup 1.0000x reference)
//
#include <hip/hip_runtime.h>
#include <hip/hip_bf16.h>

typedef __bf16 bf16x8 __attribute__((ext_vector_type(8)));
typedef float  f32x4  __attribute__((ext_vector_type(4)));
typedef short  s16x8  __attribute__((ext_vector_type(8)));
typedef unsigned short u16;

// round-to-nearest-even fp32 -> bf16 (as u16 bits)
static __device__ __forceinline__ u16 f2bf_rne(float f) {
  union { float f; unsigned u; } x; x.f = f;
  unsigned r = x.u + 0x7fffu + ((x.u >> 16) & 1u);
  return (u16)(r >> 16);
}

// split fp32 into bf16 hi (truncated) + bf16 lo (exact residual, truncated):
// f = hi + lo + O(2^-16 |f|)
static __device__ __forceinline__ void splitbf(float f, short& hi, short& lo) {
  union { float f; unsigned u; } x; x.f = f;
  hi = (short)(x.u >> 16);
  union { unsigned u; float f; } h; h.u = x.u & 0xffff0000u;
  union { float f; unsigned u; } y; y.f = f - h.f;   // exact
  lo = (short)(y.u >> 16);
}

// One wave per row: S = Q^T K (contract over head axis h), softmax over e,
// Out = V P^T.  Q/K fragments gathered directly from global (each element
// used exactly once -> LDS staging has no reuse to exploit); only the
// P matrix (C-layout -> A/B-layout transform) round-trips through LDS.
__global__ __launch_bounds__(256, 2)
void attn64_kernel(const float* __restrict__ q, const float* __restrict__ k,
                   const float* __restrict__ v, float* __restrict__ out)
{
  __shared__ u16 plds[4][4608];   // per-wave P: 64 rows x 72 u16 (144B rows, 16B-aligned)
  const int tid  = threadIdx.x;
  const int wid  = tid >> 6;
  const int lane = tid & 63;
  const int quad = lane >> 4;
  const int lo   = lane & 15;
  const int row  = blockIdx.x * 4 + wid;

  u16* P = plds[wid];
  const float* qrow = q + (size_t)row * 4096;
  const float* krow = k + (size_t)row * 4096;
  const float* vrow = v + (size_t)row * 4096;
  float*       orow = out + (size_t)row * 4096;

  // ---- Matmul 1: S[d][e] = sum_h Q[h][d] * K[h][e], fp32 via bf16 hi/lo split.
  f32x4 acc[4][4];
#pragma unroll
  for (int i = 0; i < 4; ++i)
#pragma unroll
    for (int j = 0; j < 4; ++j) acc[i][j] = (f32x4){0.f, 0.f, 0.f, 0.f};

#pragma unroll
  for (int ks = 0; ks < 2; ++ks) {
    const int hb = ks * 32 + quad * 8;       // A[m][k=quad*8+j], k chunk = ks
    float xq[4][8], xk[4][8];
#pragma unroll
    for (int t = 0; t < 4; ++t)
#pragma unroll
      for (int j = 0; j < 8; ++j) {
        const int idx = (hb + j) * 64 + lo + 16 * t;  // 16 lanes -> 16 consecutive floats
        xq[t][j] = qrow[idx];
        xk[t][j] = krow[idx];
      }
    s16x8 aqh[4], aql[4], bkh[4], bkl[4];
#pragma unroll
    for (int t = 0; t < 4; ++t)
#pragma unroll
      for (int j = 0; j < 8; ++j) {
        short h0, l0;
        splitbf(xq[t][j], h0, l0); aqh[t][j] = h0; aql[t][j] = l0;
        splitbf(xk[t][j], h0, l0); bkh[t][j] = h0; bkl[t][j] = l0;
      }
#pragma unroll
    for (int dt = 0; dt < 4; ++dt)
#pragma unroll
      for (int et = 0; et < 4; ++et) {
        bf16x8 ah = __builtin_bit_cast(bf16x8, aqh[dt]);
        bf16x8 al = __builtin_bit_cast(bf16x8, aql[dt]);
        bf16x8 bh = __builtin_bit_cast(bf16x8, bkh[et]);
        bf16x8 bl = __builtin_bit_cast(bf16x8, bkl[et]);
        acc[dt][et] = __builtin_amdgcn_mfma_f32_16x16x32_bf16(ah, bh, acc[dt][et], 0, 0, 0);
        acc[dt][et] = __builtin_amdgcn_mfma_f32_16x16x32_bf16(ah, bl, acc[dt][et], 0, 0, 0);
        acc[dt][et] = __builtin_amdgcn_mfma_f32_16x16x32_bf16(al, bh, acc[dt][et], 0, 0, 0);
      }
  }

  // ---- Prefetch V (A-operand of matmul 2) from global: contiguous dwordx4 pairs.
  // A[m=h=lo+16mt][k=e=quad*8+ks*32+j]
  bf16x8 av[2][4];
#pragma unroll
  for (int ks = 0; ks < 2; ++ks)
#pragma unroll
    for (int mt = 0; mt < 4; ++mt) {
      const float* p = vrow + (lo + 16 * mt) * 64 + quad * 8 + ks * 32;
      f32x4 v0 = *(const f32x4*)p;
      f32x4 v1 = *(const f32x4*)(p + 4);
      s16x8 t;
#pragma unroll
      for (int j = 0; j < 4; ++j) { t[j] = (short)f2bf_rne(v0[j]); t[4 + j] = (short)f2bf_rne(v1[j]); }
      av[ks][mt] = __builtin_bit_cast(bf16x8, t);
    }

  // ---- Softmax over e per row d.  C layout: acc[dt][et][r] = S[16dt+quad*4+r][16et+lo]
#pragma unroll
  for (int dt = 0; dt < 4; ++dt)
#pragma unroll
    for (int r = 0; r < 4; ++r) {
      float m = fmaxf(fmaxf(acc[dt][0][r], acc[dt][1][r]),
                      fmaxf(acc[dt][2][r], acc[dt][3][r]));
#pragma unroll
      for (int off = 1; off < 16; off <<= 1) m = fmaxf(m, __shfl_xor(m, off));
      float s = 0.f;
#pragma unroll
      for (int et = 0; et < 4; ++et) {
        float e0 = __expf(acc[dt][et][r] - m);
        acc[dt][et][r] = e0;
        s += e0;
      }
#pragma unroll
      for (int off = 1; off < 16; off <<= 1) s += __shfl_xor(s, off);
      float rs = 1.0f / s;
#pragma unroll
      for (int et = 0; et < 4; ++et) acc[dt][et][r] *= rs;
    }

  // ---- P -> LDS (bf16, row stride 72 elems = 144B).
#pragma unroll
  for (int dt = 0; dt < 4; ++dt)
#pragma unroll
    for (int r = 0; r < 4; ++r) {
      const int d = quad * 4 + r + 16 * dt;
#pragma unroll
      for (int et = 0; et < 4; ++et)
        P[d * 72 + lo + 16 * et] = f2bf_rne(acc[dt][et][r]);
    }
  __syncthreads();

  // ---- Matmul 2: Out[h][d] = sum_e V[h][e] * P[d][e]
  f32x4 acc2[4][4];
#pragma unroll
  for (int i = 0; i < 4; ++i)
#pragma unroll
    for (int j = 0; j < 4; ++j) acc2[i][j] = (f32x4){0.f, 0.f, 0.f, 0.f};

#pragma unroll
  for (int ks = 0; ks < 2; ++ks) {
    bf16x8 bp[4];
#pragma unroll
    for (int nt = 0; nt < 4; ++nt)   // B[k=e=quad*8+ks*32+j][n=d=lo+16nt], contiguous in e
      bp[nt] = *(const bf16x8*)&P[(lo + 16 * nt) * 72 + quad * 8 + ks * 32];
#pragma unroll
    for (int mt = 0; mt < 4; ++mt)
#pragma unroll
      for (int nt = 0; nt < 4; ++nt)
        acc2[mt][nt] = __builtin_amdgcn_mfma_f32_16x16x32_bf16(av[ks][mt], bp[nt], acc2[mt][nt], 0, 0, 0);
  }

  // ---- Store fp32: out[h*64+d], h = 16mt+quad*4+r, d = lo+16nt.
#pragma unroll
  for (int mt = 0; mt < 4; ++mt)
#pragma unroll
    for (int r = 0; r < 4; ++r) {
      const int h = quad * 4 + r + 16 * mt;
#pragma unroll
      for (int nt = 0; nt < 4; ++nt)
        orow[h * 64 + lo + 16 * nt] = acc2[mt][nt][r];
    }
}

extern "C" void kernel_launch(void* const* d_in, const int* in_sizes, int n_in,
                              void* d_out, int out_size, void* d_ws, size_t ws_size,
                              hipStream_t stream) {
  const float* q = (const float*)d_in[0];
  const float* k = (const float*)d_in[1];
  const float* v = (const float*)d_in[2];
  float* o = (float*)d_out;
  // 4096 rows, 1 wave/row, 4 waves per 256-thread block -> 1024 blocks.
  hipLaunchKernelGGL(attn64_kernel, dim3(1024), dim3(256), 0, stream, q, k, v, o);
}

// Round 3
// 221.646 us; speedup vs baseline: 1.0126x; 1.0126x over previous
//
#include <hip/hip_runtime.h>
#include <hip/hip_bf16.h>

typedef __bf16 bf16x8 __attribute__((ext_vector_type(8)));
typedef float  f32x4  __attribute__((ext_vector_type(4)));
typedef short  s16x8  __attribute__((ext_vector_type(8)));
typedef unsigned short u16;

// round-to-nearest-even fp32 -> bf16 (as u16 bits)
static __device__ __forceinline__ u16 f2bf_rne(float f) {
  union { float f; unsigned u; } x; x.f = f;
  unsigned r = x.u + 0x7fffu + ((x.u >> 16) & 1u);
  return (u16)(r >> 16);
}

// split fp32 into bf16 hi (truncated) + bf16 lo (exact residual, truncated)
static __device__ __forceinline__ void splitbf(float f, short& hi, short& lo) {
  union { float f; unsigned u; } x; x.f = f;
  hi = (short)(x.u >> 16);
  union { unsigned u; float f; } h; h.u = x.u & 0xffff0000u;
  union { float f; unsigned u; } y; y.f = f - h.f;   // exact (Sterbenz)
  lo = (short)(y.u >> 16);
}

// One wave per row. S = Q^T K (contract over h), softmax over e, Out = V P^T.
// Strategy vs round 2: the 128 Q/K gather dwords are issued in TWO large
// batches (all-K, then all-Q) with conversion/MFMA between them, instead of
// ~16 small register-starved batches -> ~4 exposed HBM round trips per wave
// instead of ~16. launch_bounds(256,2) gives the scheduler a 256-reg budget.
// No __syncthreads anywhere: the P LDS buffer is strictly per-wave.
__global__ __launch_bounds__(256, 2)
void attn64_kernel(const float* __restrict__ q, const float* __restrict__ k,
                   const float* __restrict__ v, float* __restrict__ out)
{
  __shared__ u16 plds[4][4608];   // per-wave P: 64 rows x 72 u16 (144B rows)
  const int tid  = threadIdx.x;
  const int wid  = tid >> 6;
  const int lane = tid & 63;
  const int quad = lane >> 4;
  const int lo   = lane & 15;
  const int row  = blockIdx.x * 4 + wid;

  u16* P = plds[wid];
  const float* qrow = q + (size_t)row * 4096;
  const float* krow = k + (size_t)row * 4096;
  const float* vrow = v + (size_t)row * 4096;
  float*       orow = out + (size_t)row * 4096;

  const int hq = quad * 8;   // this quad's h sub-block within a 32-chunk

  // ---- Batch 1: ALL K fragment dwords (64 loads), then convert.
  // frag slot [ks*4+et][j] <- K[h=ks*32+hq+j][e=lo+16*et]
  float xk[8][8];
#pragma unroll
  for (int ks = 0; ks < 2; ++ks)
#pragma unroll
    for (int et = 0; et < 4; ++et)
#pragma unroll
      for (int j = 0; j < 8; ++j)
        xk[ks * 4 + et][j] = krow[(ks * 32 + hq + j) * 64 + lo + 16 * et];

  s16x8 kh[8], kl[8];
#pragma unroll
  for (int i = 0; i < 8; ++i)
#pragma unroll
    for (int j = 0; j < 8; ++j) {
      short h0, l0; splitbf(xk[i][j], h0, l0);
      kh[i][j] = h0; kl[i][j] = l0;
    }

  // ---- Batch 2: ALL Q fragment dwords (64 loads), then convert.
  float xq[8][8];
#pragma unroll
  for (int ks = 0; ks < 2; ++ks)
#pragma unroll
    for (int dt = 0; dt < 4; ++dt)
#pragma unroll
      for (int j = 0; j < 8; ++j)
        xq[ks * 4 + dt][j] = qrow[(ks * 32 + hq + j) * 64 + lo + 16 * dt];

  s16x8 qh[8], ql[8];
#pragma unroll
  for (int i = 0; i < 8; ++i)
#pragma unroll
    for (int j = 0; j < 8; ++j) {
      short h0, l0; splitbf(xq[i][j], h0, l0);
      qh[i][j] = h0; ql[i][j] = l0;
    }

  // ---- Batch 3 (issue now, consume after softmax): V as bf16 A-frags.
  // A[m=h=lo+16mt][k=e=quad*8+ks*32+j] -> two contiguous dwordx4 per frag.
  f32x4 xv[8][2];
#pragma unroll
  for (int ks = 0; ks < 2; ++ks)
#pragma unroll
    for (int mt = 0; mt < 4; ++mt) {
      const float* p = vrow + (lo + 16 * mt) * 64 + quad * 8 + ks * 32;
      xv[ks * 4 + mt][0] = *(const f32x4*)p;
      xv[ks * 4 + mt][1] = *(const f32x4*)(p + 4);
    }

  // ---- Matmul 1: 96 MFMAs (hi*hi + hi*lo + lo*hi).
  f32x4 acc[4][4];
#pragma unroll
  for (int i = 0; i < 4; ++i)
#pragma unroll
    for (int j = 0; j < 4; ++j) acc[i][j] = (f32x4){0.f, 0.f, 0.f, 0.f};

#pragma unroll
  for (int ks = 0; ks < 2; ++ks)
#pragma unroll
    for (int dt = 0; dt < 4; ++dt) {
      bf16x8 ah = __builtin_bit_cast(bf16x8, qh[ks * 4 + dt]);
      bf16x8 al = __builtin_bit_cast(bf16x8, ql[ks * 4 + dt]);
#pragma unroll
      for (int et = 0; et < 4; ++et) {
        bf16x8 bh = __builtin_bit_cast(bf16x8, kh[ks * 4 + et]);
        bf16x8 bl = __builtin_bit_cast(bf16x8, kl[ks * 4 + et]);
        acc[dt][et] = __builtin_amdgcn_mfma_f32_16x16x32_bf16(ah, bh, acc[dt][et], 0, 0, 0);
        acc[dt][et] = __builtin_amdgcn_mfma_f32_16x16x32_bf16(ah, bl, acc[dt][et], 0, 0, 0);
        acc[dt][et] = __builtin_amdgcn_mfma_f32_16x16x32_bf16(al, bh, acc[dt][et], 0, 0, 0);
      }
    }

  // ---- Softmax over e per row d. C layout: acc[dt][et][r] = S[16dt+quad*4+r][16et+lo]
#pragma unroll
  for (int dt = 0; dt < 4; ++dt)
#pragma unroll
    for (int r = 0; r < 4; ++r) {
      float m = fmaxf(fmaxf(acc[dt][0][r], acc[dt][1][r]),
                      fmaxf(acc[dt][2][r], acc[dt][3][r]));
#pragma unroll
      for (int off = 1; off < 16; off <<= 1) m = fmaxf(m, __shfl_xor(m, off));
      float s = 0.f;
#pragma unroll
      for (int et = 0; et < 4; ++et) {
        float e0 = __expf(acc[dt][et][r] - m);
        acc[dt][et][r] = e0;
        s += e0;
      }
#pragma unroll
      for (int off = 1; off < 16; off <<= 1) s += __shfl_xor(s, off);
      float rs = 1.0f / s;
#pragma unroll
      for (int et = 0; et < 4; ++et) acc[dt][et][r] *= rs;
    }

  // ---- Convert V frags (loads have long since landed).
  bf16x8 av[8];
#pragma unroll
  for (int i = 0; i < 8; ++i) {
    s16x8 t;
#pragma unroll
    for (int j = 0; j < 4; ++j) {
      t[j]     = (short)f2bf_rne(xv[i][0][j]);
      t[4 + j] = (short)f2bf_rne(xv[i][1][j]);
    }
    av[i] = __builtin_bit_cast(bf16x8, t);
  }

  // ---- P -> LDS (bf16, row stride 72 elems). Per-wave buffer, no barrier.
#pragma unroll
  for (int dt = 0; dt < 4; ++dt)
#pragma unroll
    for (int r = 0; r < 4; ++r) {
      const int d = quad * 4 + r + 16 * dt;
#pragma unroll
      for (int et = 0; et < 4; ++et)
        P[d * 72 + lo + 16 * et] = f2bf_rne(acc[dt][et][r]);
    }

  // ---- Matmul 2: Out[h][d] = sum_e V[h][e] * P[d][e]  (32 MFMAs).
  f32x4 acc2[4][4];
#pragma unroll
  for (int i = 0; i < 4; ++i)
#pragma unroll
    for (int j = 0; j < 4; ++j) acc2[i][j] = (f32x4){0.f, 0.f, 0.f, 0.f};

#pragma unroll
  for (int ks = 0; ks < 2; ++ks) {
    bf16x8 bp[4];
#pragma unroll
    for (int nt = 0; nt < 4; ++nt)   // B[k=e=quad*8+ks*32+j][n=d=lo+16nt]
      bp[nt] = *(const bf16x8*)&P[(lo + 16 * nt) * 72 + quad * 8 + ks * 32];
#pragma unroll
    for (int mt = 0; mt < 4; ++mt)
#pragma unroll
      for (int nt = 0; nt < 4; ++nt)
        acc2[mt][nt] = __builtin_amdgcn_mfma_f32_16x16x32_bf16(av[ks * 4 + mt], bp[nt], acc2[mt][nt], 0, 0, 0);
  }

  // ---- Store fp32: out[h*64+d], h = 16mt+quad*4+r, d = lo+16nt.
#pragma unroll
  for (int mt = 0; mt < 4; ++mt)
#pragma unroll
    for (int r = 0; r < 4; ++r) {
      const int h = quad * 4 + r + 16 * mt;
#pragma unroll
      for (int nt = 0; nt < 4; ++nt)
        orow[h * 64 + lo + 16 * nt] = acc2[mt][nt][r];
    }
}

extern "C" void kernel_launch(void* const* d_in, const int* in_sizes, int n_in,
                              void* d_out, int out_size, void* d_ws, size_t ws_size,
                              hipStream_t stream) {
  const float* q = (const float*)d_in[0];
  const float* k = (const float*)d_in[1];
  const float* v = (const float*)d_in[2];
  float* o = (float*)d_out;
  hipLaunchKernelGGL(attn64_kernel, dim3(1024), dim3(256), 0, stream, q, k, v, o);
}